// Round 14
// baseline (148.316 us; speedup 1.0000x reference)
//
#include <hip/hip_runtime.h>
#include <math.h>

#define N_NODES 100000
#define N_EDGES 1600000

#define SB_LOG 10
#define SBW 1024                              // nodes per coarse bucket
#define NSB ((N_NODES + SBW - 1) / SBW)       // 98 coarse buckets
#define CAP 18000   // per-bucket capacity; mean 16327, sigma~128 -> +13 sigma

#define GS 800                                // scatter blocks
#define EPS (N_EDGES / GS)                    // 2000 edges per block (exact)
#define EPS4 (EPS / 4)                        // 500 int4 per block

#define NT_BLOCKS ((N_NODES + 63) / 64)       // 1563 nodeT blocks (64 nodes each)

// ---------------------------------------------------------------------------
// K1 (fused): blocks [0, GS) = edge scatter into fixed-capacity coarse
// 1024-node-bucket regions (int4 loads, LDS rank over 98 counters, ONE global
// cursor atomic per (block,bucket); packed record ((dst&1023)<<17 | src)).
// Scatter blocks FIRST — they are the long pole.
// Blocks [GS, GS+NT_BLOCKS): nodeT = feat @ Q + c where Q = W_in @ P (64x4),
// c = b_in @ P, P = [W_u, W_out[:,0], W_out[:,1], W_v] — the hidden 64-dim
// layer is algebraically collapsed away (everything downstream is linear in h).
// ---------------------------------------------------------------------------
__global__ __launch_bounds__(256) void prep_kernel(
    const float* __restrict__ feat,
    const float* __restrict__ W_in,
    const float* __restrict__ b_in,
    const float* __restrict__ W_edge,
    const float* __restrict__ W_out,
    const int*   __restrict__ src,
    const int*   __restrict__ dst,
    int* __restrict__ cursor,
    int* __restrict__ ework,
    float4* __restrict__ nodeT)
{
    const int tid = threadIdx.x;

    // ---------------- scatter blocks ----------------
    if ((int)blockIdx.x < GS) {
        __shared__ int hist[NSB];
        __shared__ int base[NSB];
        for (int i = tid; i < NSB; i += 256) hist[i] = 0;
        __syncthreads();

        const int4* src4 = (const int4*)src;
        const int4* dst4 = (const int4*)dst;
        const int   b40  = (blockIdx.x * EPS) >> 2;

        int bb[8], rr[8], pk[8];
        #pragma unroll
        for (int j = 0; j < 2; ++j) {
            const int o4 = j * 256 + tid;
            if (o4 < EPS4) {
                const int4 d4 = dst4[b40 + o4];
                const int4 s4 = src4[b40 + o4];
                const int dv[4] = {d4.x, d4.y, d4.z, d4.w};
                const int sv[4] = {s4.x, s4.y, s4.z, s4.w};
                #pragma unroll
                for (int u = 0; u < 4; ++u) {
                    const int idx = j * 4 + u;
                    const int d = dv[u];
                    const int b = d >> SB_LOG;
                    bb[idx] = b;
                    rr[idx] = atomicAdd(&hist[b], 1);
                    pk[idx] = ((d & (SBW - 1)) << 17) | sv[u];
                }
            }
        }
        __syncthreads();

        for (int b = tid; b < NSB; b += 256) {
            const int c = hist[b];
            if (c) base[b] = atomicAdd(&cursor[b], c);   // one global atomic
        }
        __syncthreads();

        #pragma unroll
        for (int j = 0; j < 2; ++j) {
            const int o4 = j * 256 + tid;
            if (o4 < EPS4) {
                #pragma unroll
                for (int u = 0; u < 4; ++u) {
                    const int idx = j * 4 + u;
                    ework[bb[idx] * CAP + base[bb[idx]] + rr[idx]] = pk[idx];
                }
            }
        }
        return;
    }

    // ---------------- nodeT blocks ----------------
    __shared__ float sP[64 * 4];   // P[m][j] row-major
    __shared__ float sQ[64 * 4];   // Q[k][j] row-major, 16B rows
    __shared__ float sc4[4];

    if (tid < 64) {
        sP[tid * 4 + 0] = W_edge[tid];            // W_u
        sP[tid * 4 + 1] = W_out[tid * 2 + 0];     // W_out[:,0]
        sP[tid * 4 + 2] = W_out[tid * 2 + 1];     // W_out[:,1]
        sP[tid * 4 + 3] = W_edge[64 + tid];       // W_v
    }
    __syncthreads();

    {   // Q[k][j] = sum_m W_in[k][m] * P[m][j]
        const int k = tid >> 2, j = tid & 3;
        float q = 0.f;
        for (int m = 0; m < 64; ++m) q += W_in[k * 64 + m] * sP[m * 4 + j];
        sQ[k * 4 + j] = q;
        if (tid < 4) {
            float cc = 0.f;
            for (int m = 0; m < 64; ++m) cc += b_in[m] * sP[m * 4 + tid];
            sc4[tid] = cc;
        }
    }
    __syncthreads();

    const int lane = tid & 63;
    const int wv   = tid >> 6;
    const int n    = (blockIdx.x - GS) * 64 + wv * 16 + (lane >> 2);
    const int ks   = (lane & 3) << 4;             // 16 k's per lane

    float p0 = 0.f, p1 = 0.f, p2 = 0.f, p3 = 0.f;
    if (n < N_NODES) {
        const float* fr = feat + (size_t)n * 64 + ks;
        #pragma unroll
        for (int i4 = 0; i4 < 4; ++i4) {
            const float4 f = *(const float4*)(fr + i4 * 4);
            const float fv[4] = {f.x, f.y, f.z, f.w};
            #pragma unroll
            for (int u = 0; u < 4; ++u) {
                const float4 q = *(const float4*)&sQ[(ks + i4 * 4 + u) * 4];
                p0 += fv[u] * q.x;
                p1 += fv[u] * q.y;
                p2 += fv[u] * q.z;
                p3 += fv[u] * q.w;
            }
        }
    }
    #pragma unroll
    for (int off = 1; off <= 2; off <<= 1) {
        p0 += __shfl_xor(p0, off);
        p1 += __shfl_xor(p1, off);
        p2 += __shfl_xor(p2, off);
        p3 += __shfl_xor(p3, off);
    }
    if (n < N_NODES && (lane & 3) == 0)
        nodeT[n] = make_float4(p0 + sc4[0], p1 + sc4[1], p2 + sc4[2], p3 + sc4[3]);
}

// ---------------------------------------------------------------------------
// K2: aggregation, NO in-bucket sort. Block (b, oct) exclusively owns the 128
// nodes b*1024 + oct*128 ... +127. It scans bucket b's whole edge region
// (int4, L2-resident after first touch; 8x read redundancy is cheap — reads,
// not writes), filters by octant (1 compare), gathers nodeT[src] (16B,
// L2-resident), sigmoid, LDS float-atomic accumulate into its private
// 128-node tile, and writes out directly. LDS 2.5 KB -> ~8 blocks/CU for
// gather-latency hiding; 784 blocks -> fine-grained CU balance.
// ---------------------------------------------------------------------------
__global__ __launch_bounds__(256) void agg_kernel(
    const int* __restrict__ ework,
    const int* __restrict__ cursor,
    const float4* __restrict__ nodeT,
    const float* __restrict__ b_edge,
    const float* __restrict__ b_out,
    float2* __restrict__ out)
{
    __shared__ float sB[128];
    __shared__ float sm0[128];
    __shared__ float sm1[128];
    __shared__ int   spres[128];

    const int bo  = blockIdx.x;
    const int b   = bo >> 3;           // coarse bucket
    const int oc  = bo & 7;            // octant within bucket
    const int tid = threadIdx.x;
    const int nb  = b * SBW + oc * 128;

    float fb0 = 0.f, fb1 = 0.f;        // deg==0 fallback, kept in registers
    if (tid < 128) {
        const int n = nb + tid;
        float4 t = make_float4(0.f, 0.f, 0.f, 0.f);
        if (n < N_NODES) t = nodeT[n];
        sB[tid] = t.w;
        fb0 = t.y; fb1 = t.z;
        sm0[tid] = 0.f; sm1[tid] = 0.f; spres[tid] = 0;
    }
    __syncthreads();

    const int cnt  = min(cursor[b], CAP);
    const int cnt4 = (cnt + 3) >> 2;
    const int4* ew4 = (const int4*)(ework + b * CAP);   // CAP*4 % 16 == 0
    const float be = b_edge[0];

    for (int i = tid; i < cnt4; i += 256) {
        const int4 v = ew4[i];
        const int ve[4] = {v.x, v.y, v.z, v.w};
        const int o0 = i * 4;
        #pragma unroll
        for (int u = 0; u < 4; ++u) {
            if (o0 + u < cnt) {
                const int p = ve[u];
                if (((p >> 24) & 7) == oc) {
                    const int dl = (p >> 17) & 127;
                    const int s  = p & 0x1FFFF;
                    const float4 t = nodeT[s];
                    const float  w = 1.0f / (1.0f + __expf(-(t.x + be + sB[dl])));
                    atomicAdd(&sm0[dl], w * t.y);
                    atomicAdd(&sm1[dl], w * t.z);
                    spres[dl] = 1;
                }
            }
        }
    }
    __syncthreads();

    if (tid < 128) {
        const int n = nb + tid;
        if (n < N_NODES) {
            const float o0 = (spres[tid] ? sm0[tid] : fb0) + b_out[0];
            const float o1 = (spres[tid] ? sm1[tid] : fb1) + b_out[1];
            out[n] = make_float2(o0, o1);
        }
    }
}

// ---------------------------------------------------------------------------
extern "C" void kernel_launch(void* const* d_in, const int* in_sizes, int n_in,
                              void* d_out, int out_size, void* d_ws, size_t ws_size,
                              hipStream_t stream) {
    const float* feat   = (const float*)d_in[0];
    const int*   src    = (const int*)d_in[1];
    const int*   dst    = (const int*)d_in[2];
    const float* W_in   = (const float*)d_in[3];
    const float* b_in   = (const float*)d_in[4];
    const float* W_edge = (const float*)d_in[5];
    const float* b_edge = (const float*)d_in[6];
    const float* W_out  = (const float*)d_in[7];
    const float* b_out  = (const float*)d_in[8];
    float2* out = (float2*)d_out;

    // workspace layout (16B-aligned blocks first)
    float4* nodeT  = (float4*)d_ws;                 // 1.6 MB
    int*    ework  = (int*)(nodeT + N_NODES);       // NSB*CAP ints (7.1 MB)
    int*    cursor = ework + NSB * CAP;             // NSB ints

    hipMemsetAsync(cursor, 0, NSB * sizeof(int), stream);

    prep_kernel<<<GS + NT_BLOCKS, 256, 0, stream>>>(
        feat, W_in, b_in, W_edge, W_out, src, dst, cursor, ework, nodeT);
    agg_kernel<<<NSB * 8, 256, 0, stream>>>(
        ework, cursor, nodeT, b_edge, b_out, out);
}

// Round 15
// 140.149 us; speedup vs baseline: 1.0583x; 1.0583x over previous
//
#include <hip/hip_runtime.h>
#include <math.h>

#define N_NODES 100000
#define N_EDGES 1600000

#define BK_LOG 8
#define BKW 256                               // nodes per bucket
#define NBK ((N_NODES + BKW - 1) / BKW)       // 391 buckets
#define CAPB 4864   // per-bucket capacity; mean 4092, sigma~64 -> +12 sigma
#define UNS4 3      // int4 load rounds in sortagg (3*512*4 = 6144 >= CAPB)

#define GS 800                                // scatter blocks
#define EPS (N_EDGES / GS)                    // 2000 edges per block (exact)
#define EPS4 (EPS / 4)                        // 500 int4 per block

#define NT_BLOCKS ((N_NODES + 63) / 64)       // 1563 nodeT blocks (64 nodes each)

// ---------------------------------------------------------------------------
// K1 (fused): blocks [0, GS) = edge scatter into fixed-capacity 256-node-
// bucket regions (int4 loads of src/dst, LDS rank, ONE global cursor atomic
// per (block,bucket); packed record ((dst&255)<<17 | src)). Scatter FIRST —
// it is the long pole, so it must own CUs from t=0.
// Blocks [GS, GS+NT_BLOCKS): nodeT = feat @ Q + c, Q = W_in @ P (64x4),
// c = b_in @ P, P = [W_u, W_out[:,0], W_out[:,1], W_v] — the hidden 64-dim
// layer is algebraically collapsed away (everything downstream is linear in h).
// ---------------------------------------------------------------------------
__global__ __launch_bounds__(256) void prep_kernel(
    const float* __restrict__ feat,
    const float* __restrict__ W_in,
    const float* __restrict__ b_in,
    const float* __restrict__ W_edge,
    const float* __restrict__ W_out,
    const int*   __restrict__ src,
    const int*   __restrict__ dst,
    int* __restrict__ cursor,
    int* __restrict__ ework,
    float4* __restrict__ nodeT)
{
    const int tid = threadIdx.x;

    // ---------------- scatter blocks ----------------
    if ((int)blockIdx.x < GS) {
        __shared__ int hist[NBK];
        __shared__ int base[NBK];
        for (int i = tid; i < NBK; i += 256) hist[i] = 0;
        __syncthreads();

        const int4* src4 = (const int4*)src;
        const int4* dst4 = (const int4*)dst;
        const int   b40  = (blockIdx.x * EPS) >> 2;

        int bb[8], rr[8], pk[8];
        #pragma unroll
        for (int j = 0; j < 2; ++j) {
            const int o4 = j * 256 + tid;
            if (o4 < EPS4) {
                const int4 d4 = dst4[b40 + o4];
                const int4 s4 = src4[b40 + o4];
                const int dv[4] = {d4.x, d4.y, d4.z, d4.w};
                const int sv[4] = {s4.x, s4.y, s4.z, s4.w};
                #pragma unroll
                for (int u = 0; u < 4; ++u) {
                    const int idx = j * 4 + u;
                    const int d = dv[u];
                    const int b = d >> BK_LOG;
                    bb[idx] = b;
                    rr[idx] = atomicAdd(&hist[b], 1);
                    pk[idx] = ((d & (BKW - 1)) << 17) | sv[u];
                }
            }
        }
        __syncthreads();

        for (int b = tid; b < NBK; b += 256) {
            const int c = hist[b];
            if (c) base[b] = atomicAdd(&cursor[b], c);   // one global atomic
        }
        __syncthreads();

        #pragma unroll
        for (int j = 0; j < 2; ++j) {
            const int o4 = j * 256 + tid;
            if (o4 < EPS4) {
                #pragma unroll
                for (int u = 0; u < 4; ++u) {
                    const int idx = j * 4 + u;
                    ework[bb[idx] * CAPB + base[bb[idx]] + rr[idx]] = pk[idx];
                }
            }
        }
        return;
    }

    // ---------------- nodeT blocks ----------------
    __shared__ float sP[64 * 4];   // P[m][j] row-major
    __shared__ float sQ[64 * 4];   // Q[k][j] row-major, 16B rows
    __shared__ float sc4[4];

    if (tid < 64) {
        sP[tid * 4 + 0] = W_edge[tid];            // W_u
        sP[tid * 4 + 1] = W_out[tid * 2 + 0];     // W_out[:,0]
        sP[tid * 4 + 2] = W_out[tid * 2 + 1];     // W_out[:,1]
        sP[tid * 4 + 3] = W_edge[64 + tid];       // W_v
    }
    __syncthreads();

    {   // Q[k][j] = sum_m W_in[k][m] * P[m][j]
        const int k = tid >> 2, j = tid & 3;
        float q = 0.f;
        for (int m = 0; m < 64; ++m) q += W_in[k * 64 + m] * sP[m * 4 + j];
        sQ[k * 4 + j] = q;
        if (tid < 4) {
            float cc = 0.f;
            for (int m = 0; m < 64; ++m) cc += b_in[m] * sP[m * 4 + tid];
            sc4[tid] = cc;
        }
    }
    __syncthreads();

    const int lane = tid & 63;
    const int wv   = tid >> 6;
    const int n    = (blockIdx.x - GS) * 64 + wv * 16 + (lane >> 2);
    const int ks   = (lane & 3) << 4;             // 16 k's per lane

    float p0 = 0.f, p1 = 0.f, p2 = 0.f, p3 = 0.f;
    if (n < N_NODES) {
        const float* fr = feat + (size_t)n * 64 + ks;
        #pragma unroll
        for (int i4 = 0; i4 < 4; ++i4) {
            const float4 f = *(const float4*)(fr + i4 * 4);
            const float fv[4] = {f.x, f.y, f.z, f.w};
            #pragma unroll
            for (int u = 0; u < 4; ++u) {
                const float4 q = *(const float4*)&sQ[(ks + i4 * 4 + u) * 4];
                p0 += fv[u] * q.x;
                p1 += fv[u] * q.y;
                p2 += fv[u] * q.z;
                p3 += fv[u] * q.w;
            }
        }
    }
    #pragma unroll
    for (int off = 1; off <= 2; off <<= 1) {
        p0 += __shfl_xor(p0, off);
        p1 += __shfl_xor(p1, off);
        p2 += __shfl_xor(p2, off);
        p3 += __shfl_xor(p3, off);
    }
    if (n < N_NODES && (lane & 3) == 0)
        nodeT[n] = make_float4(p0 + sc4[0], p1 + sc4[1], p2 + sc4[2], p3 + sc4[3]);
}

// ---------------------------------------------------------------------------
// K2: fused fine-sort + aggregation + output. One block per 256-node bucket.
// int4 loads of the bucket region, LDS rank by node, 256-wide scan, place
// src into LDS ssorted, then 4 lanes per node (2 passes of 128 nodes) stream
// its run: gather nodeT[src] (16B, L2-resident), sigmoid, register-acc,
// quad shfl-combine, write out. No global atomics; writes only the output.
// ---------------------------------------------------------------------------
__global__ __launch_bounds__(512) void sortagg_kernel(
    const int* __restrict__ ework,
    const int* __restrict__ cursor,
    const float4* __restrict__ nodeT,
    const float* __restrict__ b_edge,
    const float* __restrict__ b_out,
    float2* __restrict__ out)
{
    __shared__ int hist[BKW];
    __shared__ int sdata[BKW];
    __shared__ int sbase[BKW];
    __shared__ int ssorted[CAPB];   // 19 KB

    const int b   = blockIdx.x;
    const int tid = threadIdx.x;

    if (tid < BKW) hist[tid] = 0;
    __syncthreads();

    const int cnt = min(cursor[b], CAPB);
    const int4* ew4 = (const int4*)(ework + b * CAPB);   // CAPB*4 % 16 == 0

    // vector load + rank (per-element tail guard)
    int4 vv[UNS4];
    int  rk[UNS4][4];
    #pragma unroll
    for (int j = 0; j < UNS4; ++j) {
        const int o = (j * 512 + tid) * 4;
        if (o < cnt) {
            const int4 v = ew4[j * 512 + tid];
            vv[j] = v;
            const int ve[4] = {v.x, v.y, v.z, v.w};
            #pragma unroll
            for (int u = 0; u < 4; ++u)
                if (o + u < cnt) rk[j][u] = atomicAdd(&hist[ve[u] >> 17], 1);
        }
    }
    __syncthreads();

    // exclusive scan over the 256 per-node counts
    int own = 0;
    if (tid < BKW) { own = hist[tid]; sdata[tid] = own; }
    __syncthreads();
    for (int off = 1; off < BKW; off <<= 1) {
        int t = 0;
        if (tid < BKW && tid >= off) t = sdata[tid - off];
        __syncthreads();
        if (tid < BKW) sdata[tid] += t;
        __syncthreads();
    }
    if (tid < BKW) sbase[tid] = sdata[tid] - own;
    __syncthreads();

    // place into LDS
    #pragma unroll
    for (int j = 0; j < UNS4; ++j) {
        const int o = (j * 512 + tid) * 4;
        if (o < cnt) {
            const int4 v = vv[j];
            const int ve[4] = {v.x, v.y, v.z, v.w};
            #pragma unroll
            for (int u = 0; u < 4; ++u)
                if (o + u < cnt)
                    ssorted[sbase[ve[u] >> 17] + rk[j][u]] = ve[u] & 0x1FFFF;
        }
    }
    __syncthreads();

    // aggregate: 4 lanes per node, 2 passes of 128 nodes
    const int sub = tid & 3;
    const float be  = b_edge[0];
    const float bo0 = b_out[0];
    const float bo1 = b_out[1];

    #pragma unroll
    for (int pass = 0; pass < 2; ++pass) {
        const int l = pass * 128 + (tid >> 2);
        const int n = b * BKW + l;

        float4 tn = make_float4(0.f, 0.f, 0.f, 0.f);
        if (n < N_NODES) tn = nodeT[n];
        const int   beg = sbase[l];
        const int   len = hist[l];
        const float Bn  = tn.w + be;

        float m0 = 0.f, m1 = 0.f;
        for (int i = sub; i < len; i += 4) {
            const int    s = ssorted[beg + i];
            const float4 t = nodeT[s];
            const float  w = 1.0f / (1.0f + __expf(-(t.x + Bn)));
            m0 += w * t.y;
            m1 += w * t.z;
        }
        m0 += __shfl_xor(m0, 1);
        m1 += __shfl_xor(m1, 1);
        m0 += __shfl_xor(m0, 2);
        m1 += __shfl_xor(m1, 2);

        if (sub == 0 && n < N_NODES) {
            const float o0 = (len ? m0 : tn.y) + bo0;
            const float o1 = (len ? m1 : tn.z) + bo1;
            out[n] = make_float2(o0, o1);
        }
    }
}

// ---------------------------------------------------------------------------
extern "C" void kernel_launch(void* const* d_in, const int* in_sizes, int n_in,
                              void* d_out, int out_size, void* d_ws, size_t ws_size,
                              hipStream_t stream) {
    const float* feat   = (const float*)d_in[0];
    const int*   src    = (const int*)d_in[1];
    const int*   dst    = (const int*)d_in[2];
    const float* W_in   = (const float*)d_in[3];
    const float* b_in   = (const float*)d_in[4];
    const float* W_edge = (const float*)d_in[5];
    const float* b_edge = (const float*)d_in[6];
    const float* W_out  = (const float*)d_in[7];
    const float* b_out  = (const float*)d_in[8];
    float2* out = (float2*)d_out;

    // workspace layout (16B-aligned blocks first)
    float4* nodeT  = (float4*)d_ws;                 // 1.6 MB
    int*    ework  = (int*)(nodeT + N_NODES);       // NBK*CAPB ints (7.6 MB)
    int*    cursor = ework + NBK * CAPB;            // NBK ints

    hipMemsetAsync(cursor, 0, NBK * sizeof(int), stream);

    prep_kernel<<<GS + NT_BLOCKS, 256, 0, stream>>>(
        feat, W_in, b_in, W_edge, W_out, src, dst, cursor, ework, nodeT);
    sortagg_kernel<<<NBK, 512, 0, stream>>>(
        ework, cursor, nodeT, b_edge, b_out, out);
}

// Round 16
// 132.649 us; speedup vs baseline: 1.1181x; 1.0565x over previous
//
#include <hip/hip_runtime.h>
#include <math.h>

#define N_NODES 100000
#define N_EDGES 1600000

#define BK_LOG 8
#define BKW 256                               // nodes per bucket
#define NBK ((N_NODES + BKW - 1) / BKW)       // 391 buckets
#define CAPB 4864   // per-bucket capacity; mean 4092, sigma~64 -> +12 sigma
#define UNS4 3      // int4 load rounds in sortagg (3*512*4 = 6144 >= CAPB)

#define GS 800                                // scatter blocks
#define EPS (N_EDGES / GS)                    // 2000 edges per block (exact)
#define EPS4 (EPS / 4)                        // 500 int4 per block

#define NT_BLOCKS ((N_NODES + 63) / 64)       // 1563 nodeT blocks (64 nodes each)

// ---------------------------------------------------------------------------
// K1 (fused): blocks [0, NT_BLOCKS) compute nodeT = feat @ Q + c where
// Q = W_in @ P (64x4), c = b_in @ P, P = [W_u, W_out[:,0], W_out[:,1], W_v]
// (hidden 64-dim layer algebraically collapsed away).
// Blocks [NT_BLOCKS, +GS): edge scatter into fixed-capacity 256-node-bucket
// regions; int4 vector loads of src/dst, LDS rank, ONE global cursor atomic
// per (block,bucket); packed record ((dst&255)<<17 | src).
// NOTE: nodeT blocks FIRST — measured best (R12 130 µs vs scatter-first
// R15 140 µs: concurrent scatter blocks contend on the write fabric; the
// interleave behind read-heavy nodeT blocks smooths demand).
// ---------------------------------------------------------------------------
__global__ __launch_bounds__(256) void prep_kernel(
    const float* __restrict__ feat,
    const float* __restrict__ W_in,
    const float* __restrict__ b_in,
    const float* __restrict__ W_edge,
    const float* __restrict__ W_out,
    const int*   __restrict__ src,
    const int*   __restrict__ dst,
    int* __restrict__ cursor,
    int* __restrict__ ework,
    float4* __restrict__ nodeT)
{
    const int tid = threadIdx.x;

    // ---------------- scatter blocks ----------------
    if ((int)blockIdx.x >= NT_BLOCKS) {
        __shared__ int hist[NBK];
        __shared__ int base[NBK];
        for (int i = tid; i < NBK; i += 256) hist[i] = 0;
        __syncthreads();

        const int4* src4 = (const int4*)src;
        const int4* dst4 = (const int4*)dst;
        const int   b40  = ((blockIdx.x - NT_BLOCKS) * EPS) >> 2;

        int bb[8], rr[8], pk[8];
        #pragma unroll
        for (int j = 0; j < 2; ++j) {
            const int o4 = j * 256 + tid;
            if (o4 < EPS4) {
                const int4 d4 = dst4[b40 + o4];
                const int4 s4 = src4[b40 + o4];
                const int dv[4] = {d4.x, d4.y, d4.z, d4.w};
                const int sv[4] = {s4.x, s4.y, s4.z, s4.w};
                #pragma unroll
                for (int u = 0; u < 4; ++u) {
                    const int idx = j * 4 + u;
                    const int d = dv[u];
                    const int b = d >> BK_LOG;
                    bb[idx] = b;
                    rr[idx] = atomicAdd(&hist[b], 1);
                    pk[idx] = ((d & (BKW - 1)) << 17) | sv[u];
                }
            }
        }
        __syncthreads();

        for (int b = tid; b < NBK; b += 256) {
            const int c = hist[b];
            if (c) base[b] = atomicAdd(&cursor[b], c);   // one global atomic
        }
        __syncthreads();

        #pragma unroll
        for (int j = 0; j < 2; ++j) {
            const int o4 = j * 256 + tid;
            if (o4 < EPS4) {
                #pragma unroll
                for (int u = 0; u < 4; ++u) {
                    const int idx = j * 4 + u;
                    ework[bb[idx] * CAPB + base[bb[idx]] + rr[idx]] = pk[idx];
                }
            }
        }
        return;
    }

    // ---------------- nodeT blocks ----------------
    __shared__ float sP[64 * 4];   // P[m][j] row-major
    __shared__ float sQ[64 * 4];   // Q[k][j] row-major, 16B rows
    __shared__ float sc[4];

    if (tid < 64) {
        sP[tid * 4 + 0] = W_edge[tid];            // W_u
        sP[tid * 4 + 1] = W_out[tid * 2 + 0];     // W_out[:,0]
        sP[tid * 4 + 2] = W_out[tid * 2 + 1];     // W_out[:,1]
        sP[tid * 4 + 3] = W_edge[64 + tid];       // W_v
    }
    __syncthreads();

    {   // Q[k][j] = sum_m W_in[k][m] * P[m][j]
        const int k = tid >> 2, j = tid & 3;
        float q = 0.f;
        for (int m = 0; m < 64; ++m) q += W_in[k * 64 + m] * sP[m * 4 + j];
        sQ[k * 4 + j] = q;
        if (tid < 4) {
            float cc = 0.f;
            for (int m = 0; m < 64; ++m) cc += b_in[m] * sP[m * 4 + tid];
            sc[tid] = cc;
        }
    }
    __syncthreads();

    const int lane = tid & 63;
    const int wv   = tid >> 6;
    const int n    = blockIdx.x * 64 + wv * 16 + (lane >> 2);  // 16 nodes/wave
    const int ks   = (lane & 3) << 4;                           // 16 k's/lane

    float p0 = 0.f, p1 = 0.f, p2 = 0.f, p3 = 0.f;
    if (n < N_NODES) {
        const float* fr = feat + (size_t)n * 64 + ks;
        #pragma unroll
        for (int i4 = 0; i4 < 4; ++i4) {
            const float4 f = *(const float4*)(fr + i4 * 4);
            const float fv[4] = {f.x, f.y, f.z, f.w};
            #pragma unroll
            for (int u = 0; u < 4; ++u) {
                const float4 q = *(const float4*)&sQ[(ks + i4 * 4 + u) * 4];
                p0 += fv[u] * q.x;
                p1 += fv[u] * q.y;
                p2 += fv[u] * q.z;
                p3 += fv[u] * q.w;
            }
        }
    }
    #pragma unroll
    for (int off = 1; off <= 2; off <<= 1) {
        p0 += __shfl_xor(p0, off);
        p1 += __shfl_xor(p1, off);
        p2 += __shfl_xor(p2, off);
        p3 += __shfl_xor(p3, off);
    }
    if (n < N_NODES && (lane & 3) == 0)
        nodeT[n] = make_float4(p0 + sc[0], p1 + sc[1], p2 + sc[2], p3 + sc[3]);
}

// ---------------------------------------------------------------------------
// K2: fused fine-sort + aggregation + output. One block per 256-node bucket.
// int4 loads of the bucket region, LDS rank by node, 256-wide scan, place
// src into LDS ssorted, then 4 lanes per node (2 passes of 128 nodes) stream
// its run: gather nodeT[src] (16B, L2-resident), sigmoid, register-acc,
// quad shfl-combine, write out. No global atomics; writes only the output.
// ---------------------------------------------------------------------------
__global__ __launch_bounds__(512) void sortagg_kernel(
    const int* __restrict__ ework,
    const int* __restrict__ cursor,
    const float4* __restrict__ nodeT,
    const float* __restrict__ b_edge,
    const float* __restrict__ b_out,
    float2* __restrict__ out)
{
    __shared__ int hist[BKW];
    __shared__ int sdata[BKW];
    __shared__ int sbase[BKW];
    __shared__ int ssorted[CAPB];   // 19 KB

    const int b   = blockIdx.x;
    const int tid = threadIdx.x;

    if (tid < BKW) hist[tid] = 0;
    __syncthreads();

    const int cnt = min(cursor[b], CAPB);
    const int4* ew4 = (const int4*)(ework + b * CAPB);   // CAPB*4 % 16 == 0

    // vector load + rank (per-element tail guard)
    int4 vv[UNS4];
    int  rk[UNS4][4];
    #pragma unroll
    for (int j = 0; j < UNS4; ++j) {
        const int o = (j * 512 + tid) * 4;
        if (o < cnt) {
            const int4 v = ew4[j * 512 + tid];
            vv[j] = v;
            const int ve[4] = {v.x, v.y, v.z, v.w};
            #pragma unroll
            for (int u = 0; u < 4; ++u)
                if (o + u < cnt) rk[j][u] = atomicAdd(&hist[ve[u] >> 17], 1);
        }
    }
    __syncthreads();

    // exclusive scan over the 256 per-node counts
    int own = 0;
    if (tid < BKW) { own = hist[tid]; sdata[tid] = own; }
    __syncthreads();
    for (int off = 1; off < BKW; off <<= 1) {
        int t = 0;
        if (tid < BKW && tid >= off) t = sdata[tid - off];
        __syncthreads();
        if (tid < BKW) sdata[tid] += t;
        __syncthreads();
    }
    if (tid < BKW) sbase[tid] = sdata[tid] - own;
    __syncthreads();

    // place into LDS
    #pragma unroll
    for (int j = 0; j < UNS4; ++j) {
        const int o = (j * 512 + tid) * 4;
        if (o < cnt) {
            const int4 v = vv[j];
            const int ve[4] = {v.x, v.y, v.z, v.w};
            #pragma unroll
            for (int u = 0; u < 4; ++u)
                if (o + u < cnt)
                    ssorted[sbase[ve[u] >> 17] + rk[j][u]] = ve[u] & 0x1FFFF;
        }
    }
    __syncthreads();

    // aggregate: 4 lanes per node, 2 passes of 128 nodes
    const int sub = tid & 3;
    const float be  = b_edge[0];
    const float bo0 = b_out[0];
    const float bo1 = b_out[1];

    #pragma unroll
    for (int pass = 0; pass < 2; ++pass) {
        const int l = pass * 128 + (tid >> 2);
        const int n = b * BKW + l;

        float4 tn = make_float4(0.f, 0.f, 0.f, 0.f);
        if (n < N_NODES) tn = nodeT[n];
        const int   beg = sbase[l];
        const int   len = hist[l];
        const float Bn  = tn.w + be;

        float m0 = 0.f, m1 = 0.f;
        for (int i = sub; i < len; i += 4) {
            const int    s = ssorted[beg + i];
            const float4 t = nodeT[s];
            const float  w = 1.0f / (1.0f + __expf(-(t.x + Bn)));
            m0 += w * t.y;
            m1 += w * t.z;
        }
        m0 += __shfl_xor(m0, 1);
        m1 += __shfl_xor(m1, 1);
        m0 += __shfl_xor(m0, 2);
        m1 += __shfl_xor(m1, 2);

        if (sub == 0 && n < N_NODES) {
            const float o0 = (len ? m0 : tn.y) + bo0;
            const float o1 = (len ? m1 : tn.z) + bo1;
            out[n] = make_float2(o0, o1);
        }
    }
}

// ---------------------------------------------------------------------------
extern "C" void kernel_launch(void* const* d_in, const int* in_sizes, int n_in,
                              void* d_out, int out_size, void* d_ws, size_t ws_size,
                              hipStream_t stream) {
    const float* feat   = (const float*)d_in[0];
    const int*   src    = (const int*)d_in[1];
    const int*   dst    = (const int*)d_in[2];
    const float* W_in   = (const float*)d_in[3];
    const float* b_in   = (const float*)d_in[4];
    const float* W_edge = (const float*)d_in[5];
    const float* b_edge = (const float*)d_in[6];
    const float* W_out  = (const float*)d_in[7];
    const float* b_out  = (const float*)d_in[8];
    float2* out = (float2*)d_out;

    // workspace layout (16B-aligned blocks first)
    float4* nodeT  = (float4*)d_ws;                 // 1.6 MB
    int*    ework  = (int*)(nodeT + N_NODES);       // NBK*CAPB ints (7.6 MB)
    int*    cursor = ework + NBK * CAPB;            // NBK ints

    hipMemsetAsync(cursor, 0, NBK * sizeof(int), stream);

    prep_kernel<<<NT_BLOCKS + GS, 256, 0, stream>>>(
        feat, W_in, b_in, W_edge, W_out, src, dst, cursor, ework, nodeT);
    sortagg_kernel<<<NBK, 512, 0, stream>>>(
        ework, cursor, nodeT, b_edge, b_out, out);
}